// Round 5
// baseline (1919.194 us; speedup 1.0000x reference)
//
#include <hip/hip_runtime.h>
#include <math.h>

#define NE     50000
#define NNODE  10000
#define HDIM   128
#define GBIN   2048
#define NLUT   2049          // GBIN+1 rows
#define NC     4160          // 576 + 3584
#define NC1    576

typedef _Float16 h2 __attribute__((ext_vector_type(2)));
typedef _Float16 h4 __attribute__((ext_vector_type(4)));
typedef _Float16 h8 __attribute__((ext_vector_type(8)));

// constants
#define SQ3C        1.7320508075688772f
#define INV_SQ3     0.5773502691896258f
#define C0_1F       0.20412414523193154f   // 1/sqrt(24)
#define C1_1_OS3F   0.20412414523193154f   // sqrt(3/24)/sqrt(3) = 1/sqrt(24)
#define C0_2F       0.05590169943749474f   // 1/sqrt(320)
#define C1_2_OS3F   0.0625f                // sqrt(3/256)/sqrt(3)
#define INV_SQRT_H  0.08838834764831845f   // 1/sqrt(128)
#define DELTA       (5.0f/2048.0f)
#define INV_DELTA   409.6f
#define STEP_INV    (51.0f/5.0f)

// ---------------- K1: LUT build (fp16 output) ----------------
__global__ __launch_bounds__(256) void k_lut(
    const float* __restrict__ lw1, const float* __restrict__ lw2,
    const float* __restrict__ rw1, const float* __restrict__ rw2,
    const float actc, const float K0C, _Float16* __restrict__ lut) {
  __shared__ float Hs[256][20];
  const int pb = blockIdx.x;
  const int t  = threadIdx.x;
  {
    const int which = t >> 7, hc = t & 127;
    const float* __restrict__ w1 = which ? rw1 : lw1;
#pragma unroll
    for (int m = 0; m < 16; ++m) {
      const int g = pb * 16 + m;
      float h = 0.f;
      if (g <= GBIN) {
        const float d  = (float)g * DELTA;
        const float tt = d * STEP_INV;
        const int   i0 = (int)floorf(tt);
        float z = 0.f;
#pragma unroll
        for (int k = 0; k < 2; ++k) {
          const int ii = i0 + k;
          if (ii >= 1 && ii <= 50) {
            const float diff = tt - (float)ii;
            const float a = diff + 1.f, b = 1.f - diff;
            if (a > 0.f && b > 0.f) {
              const float val = K0C * __expf(-1.f / a - 1.f / b);
              z += val * w1[(ii - 1) * HDIM + hc];
            }
          }
        }
        h = actc * z / (1.f + __expf(-z)) * INV_SQRT_H;
      }
      Hs[t][m] = h;
    }
  }
  __syncthreads();

  const int n0 = blockIdx.y * 1024 + t * 4;
  if (n0 >= NC) return;
  const int isrec = (n0 >= NC1);
  const float* __restrict__ w2 = isrec ? (rw2 + (n0 - NC1)) : (lw2 + n0);
  const int stride = isrec ? 3584 : 576;
  const int hbase  = isrec ? 128 : 0;

  float acc[4][16];
#pragma unroll
  for (int c = 0; c < 4; ++c)
#pragma unroll
    for (int m = 0; m < 16; ++m) acc[c][m] = 0.f;

#pragma unroll 2
  for (int h = 0; h < HDIM; ++h) {
    const float4 wv = *(const float4*)(w2 + (size_t)h * stride);
    const float* hp = &Hs[hbase + h][0];
    const float4 m0 = *(const float4*)(hp);
    const float4 m1 = *(const float4*)(hp + 4);
    const float4 m2 = *(const float4*)(hp + 8);
    const float4 m3 = *(const float4*)(hp + 12);
    float hm[16];
    hm[0]=m0.x; hm[1]=m0.y; hm[2]=m0.z; hm[3]=m0.w;
    hm[4]=m1.x; hm[5]=m1.y; hm[6]=m1.z; hm[7]=m1.w;
    hm[8]=m2.x; hm[9]=m2.y; hm[10]=m2.z; hm[11]=m2.w;
    hm[12]=m3.x; hm[13]=m3.y; hm[14]=m3.z; hm[15]=m3.w;
    float wc[4]; wc[0]=wv.x; wc[1]=wv.y; wc[2]=wv.z; wc[3]=wv.w;
#pragma unroll
    for (int c = 0; c < 4; ++c)
#pragma unroll
      for (int m = 0; m < 16; ++m) acc[c][m] += wc[c] * hm[m];
  }

#pragma unroll
  for (int m = 0; m < 16; ++m) {
    const int g = pb * 16 + m;
    if (g <= GBIN) {
      h4 o;
      o[0] = (_Float16)acc[0][m]; o[1] = (_Float16)acc[1][m];
      o[2] = (_Float16)acc[2][m]; o[3] = (_Float16)acc[3][m];
      *(h4*)(lut + (size_t)g * NC + n0) = o;
    }
  }
}

// ---------------- K2: per-edge bin/frac + histogram; zero inactive outputs ----------------
__global__ void k_edge(const int* __restrict__ ei, const float* __restrict__ pos,
                       float* __restrict__ out, int* __restrict__ bin_e,
                       float* __restrict__ f_e, int* __restrict__ cnt) {
  const int e = blockIdx.x * 256 + threadIdx.x;
  if (e >= NE) return;
  const int rec = ei[e], lig = ei[NE + e];
  const float ax = pos[lig * 3 + 0] - pos[rec * 3 + 0];
  const float ay = pos[lig * 3 + 1] - pos[rec * 3 + 1];
  const float az = pos[lig * 3 + 2] - pos[rec * 3 + 2];
  const float d = sqrtf(ax * ax + ay * ay + az * az);
  if (d > 0.f && d < 5.0f) {
    const float tf = d * INV_DELTA;
    int b = (int)tf;
    if (b > GBIN - 1) b = GBIN - 1;
    bin_e[e] = b;
    f_e[e] = tf - (float)b;
    atomicAdd(&cnt[b], 1);
  } else {
    bin_e[e] = -1;
    float* o = out + (size_t)e * 20;
#pragma unroll
    for (int i2 = 0; i2 < 20; ++i2) o[i2] = 0.f;
  }
}

// ---------------- K3a: exclusive scan of 2048 bin counts ----------------
__global__ void k_scan(const int* __restrict__ cnt, int* __restrict__ offs,
                       int* __restrict__ woff) {
  __shared__ int lds[256];
  const int t = threadIdx.x;
  int loc[8];
  int s = 0;
#pragma unroll
  for (int i = 0; i < 8; ++i) { loc[i] = cnt[t * 8 + i]; s += loc[i]; }
  lds[t] = s;
  __syncthreads();
  for (int o = 1; o < 256; o <<= 1) {
    int v = 0;
    if (t >= o) v = lds[t - o];
    __syncthreads();
    lds[t] += v;
    __syncthreads();
  }
  int run = lds[t] - s;
#pragma unroll
  for (int i = 0; i < 8; ++i) {
    offs[t * 8 + i] = run;
    woff[t * 8 + i] = run;
    run += loc[i];
  }
  if (t == 255) offs[GBIN] = run;
}

// ---------------- K3b: counting-sort scatter ----------------
__global__ void k_scatter(const int* __restrict__ bin_e, int* __restrict__ woff,
                          int* __restrict__ sorted) {
  const int e = blockIdx.x * 256 + threadIdx.x;
  if (e >= NE) return;
  const int b = bin_e[e];
  if (b >= 0) {
    const int p = atomicAdd(&woff[b], 1);
    sorted[p] = e;
  }
}

// ---------------- K4: epilogue: one bin per 64-thread block, fp16 LUT rows in LDS --------
// 16 quads; 4 lanes per edge. Layer 1 output-split, quad allgather via shfl,
// layer 2 interleaved v-split (v = vv*4+s) with single accumulator set per row pass.
__global__ __launch_bounds__(64, 3) void k_epi(
    const _Float16* __restrict__ lut, const int* __restrict__ offs,
    const int* __restrict__ sorted, const float* __restrict__ f_e,
    const int* __restrict__ ei, const float* __restrict__ pos,
    const float* __restrict__ x, float* __restrict__ out) {
  __shared__ uint4 Wl4[1040];          // 2 rows x 4160 fp16 = 16640 B
  const int b = blockIdx.x;
  const int beg = offs[b];
  const int count = offs[b + 1] - beg;
  if (count == 0) return;
  const int tid = threadIdx.x;
  {
    const uint4* src = (const uint4*)(lut + (size_t)b * NC);
    for (int i = tid; i < 1040; i += 64) Wl4[i] = src[i];
  }
  __syncthreads();
  const _Float16* __restrict__ W0 = (const _Float16*)Wl4;
  const _Float16* __restrict__ W1 = W0 + NC;
  const int s  = tid & 3;
  const int qb = tid & ~3;   // quad base lane (block = 1 wave)

  for (int slot = tid >> 2; slot < count; slot += 16) {
    const int e = sorted[beg + slot];
    const float f = f_e[e];
    const int rec = ei[e], lig = ei[NE + e];
    const float ax = pos[lig * 3 + 0] - pos[rec * 3 + 0];
    const float ay = pos[lig * 3 + 1] - pos[rec * 3 + 1];
    const float az = pos[lig * 3 + 2] - pos[rec * 3 + 2];
    const float d = sqrtf(ax * ax + ay * ay + az * az);
    const float inv = SQ3C / fmaxf(d, 1e-12f);
    const float sh0 = ax * inv, sh1 = ay * inv, sh2 = az * inv;

    // ---- lig features ----
    float s1[16], v1[24];
    {
      const float4* xl = (const float4*)(x + (size_t)lig * 40);
#pragma unroll
      for (int j = 0; j < 4; ++j) {
        float4 v = xl[j];
        s1[j * 4 + 0] = v.x; s1[j * 4 + 1] = v.y; s1[j * 4 + 2] = v.z; s1[j * 4 + 3] = v.w;
      }
#pragma unroll
      for (int j = 0; j < 6; ++j) {
        float4 v = xl[4 + j];
        v1[j * 4 + 0] = v.x; v1[j * 4 + 1] = v.y; v1[j * 4 + 2] = v.z; v1[j * 4 + 3] = v.w;
      }
    }
    float vs[8];
#pragma unroll
    for (int u = 0; u < 8; ++u)
      vs[u] = (v1[u * 3] * sh0 + v1[u * 3 + 1] * sh1 + v1[u * 3 + 2] * sh2) * INV_SQ3;

    // ---- layer 1: sa (lane owns w = 4s..4s+3) ----
    float A0[4] = {0.f, 0.f, 0.f, 0.f}, A1[4] = {0.f, 0.f, 0.f, 0.f};
#pragma unroll
    for (int u = 0; u < 16; ++u) {   // W000 @ 0: [u:16][w:16]
      h4 w0 = *(const h4*)(W0 + u * 16 + s * 4);
      h4 w1 = *(const h4*)(W1 + u * 16 + s * 4);
      const float su = s1[u];
      A0[0] += (float)w0[0] * su; A0[1] += (float)w0[1] * su;
      A0[2] += (float)w0[2] * su; A0[3] += (float)w0[3] * su;
      A1[0] += (float)w1[0] * su; A1[1] += (float)w1[1] * su;
      A1[2] += (float)w1[2] * su; A1[3] += (float)w1[3] * su;
    }
#pragma unroll
    for (int u = 0; u < 8; ++u) {    // W110 @ 448: [u:8][w:16]
      h4 w0 = *(const h4*)(W0 + 448 + u * 16 + s * 4);
      h4 w1 = *(const h4*)(W1 + 448 + u * 16 + s * 4);
      const float su = vs[u];
      A0[0] += (float)w0[0] * su; A0[1] += (float)w0[1] * su;
      A0[2] += (float)w0[2] * su; A0[3] += (float)w0[3] * su;
      A1[0] += (float)w1[0] * su; A1[1] += (float)w1[1] * su;
      A1[2] += (float)w1[2] * su; A1[3] += (float)w1[3] * su;
    }
    const float sa0 = C0_1F * (A0[0] + f * (A1[0] - A0[0]));
    const float sa1 = C0_1F * (A0[1] + f * (A1[1] - A0[1]));
    const float sa2 = C0_1F * (A0[2] + f * (A1[2] - A0[2]));
    const float sa3 = C0_1F * (A0[3] + f * (A1[3] - A0[3]));

    // ---- layer 1: va (lane owns w = 2s, 2s+1) ----
    float vaA0, vaA1, vaA2, vaB0, vaB1, vaB2;
    {
      float cA0 = 0.f, cB0 = 0.f, cA1 = 0.f, cB1 = 0.f;
#pragma unroll
      for (int u = 0; u < 16; ++u) {  // W011 @ 256: [u:16][w:8]
        h2 w0 = *(const h2*)(W0 + 256 + u * 8 + s * 2);
        h2 w1 = *(const h2*)(W1 + 256 + u * 8 + s * 2);
        const float su = s1[u];
        cA0 += (float)w0[0] * su; cB0 += (float)w0[1] * su;
        cA1 += (float)w1[0] * su; cB1 += (float)w1[1] * su;
      }
      float tA0x=0.f,tA0y=0.f,tA0z=0.f, tB0x=0.f,tB0y=0.f,tB0z=0.f;
      float tA1x=0.f,tA1y=0.f,tA1z=0.f, tB1x=0.f,tB1y=0.f,tB1z=0.f;
#pragma unroll
      for (int u = 0; u < 8; ++u) {   // W101 @ 384: [u:8][w:8]
        h2 w0 = *(const h2*)(W0 + 384 + u * 8 + s * 2);
        h2 w1 = *(const h2*)(W1 + 384 + u * 8 + s * 2);
        const float p0 = v1[u * 3], p1 = v1[u * 3 + 1], p2 = v1[u * 3 + 2];
        const float a0 = (float)w0[0], b0v = (float)w0[1];
        const float a1 = (float)w1[0], b1v = (float)w1[1];
        tA0x += a0 * p0; tA0y += a0 * p1; tA0z += a0 * p2;
        tB0x += b0v * p0; tB0y += b0v * p1; tB0z += b0v * p2;
        tA1x += a1 * p0; tA1y += a1 * p1; tA1z += a1 * p2;
        tB1x += b1v * p0; tB1y += b1v * p1; tB1z += b1v * p2;
      }
      const float cA = cA0 + f * (cA1 - cA0);
      const float cB = cB0 + f * (cB1 - cB0);
      vaA0 = C1_1_OS3F * (cA * sh0 + (tA0x + f * (tA1x - tA0x)));
      vaA1 = C1_1_OS3F * (cA * sh1 + (tA0y + f * (tA1y - tA0y)));
      vaA2 = C1_1_OS3F * (cA * sh2 + (tA0z + f * (tA1z - tA0z)));
      vaB0 = C1_1_OS3F * (cB * sh0 + (tB0x + f * (tB1x - tB0x)));
      vaB1 = C1_1_OS3F * (cB * sh1 + (tB0y + f * (tB1y - tB0y)));
      vaB2 = C1_1_OS3F * (cB * sh2 + (tB0z + f * (tB1z - tB0z)));
    }

    // ---- quad allgather ----
    float saF[16];
#pragma unroll
    for (int k = 0; k < 16; ++k) {
      const float v = ((k & 3) == 0) ? sa0 : ((k & 3) == 1) ? sa1 : ((k & 3) == 2) ? sa2 : sa3;
      saF[k] = __shfl(v, qb + (k >> 2), 64);
    }
    float vaF[24];
#pragma unroll
    for (int w = 0; w < 8; ++w) {
      const int src = qb + (w >> 1);
      const float x0 = (w & 1) ? vaB0 : vaA0;
      const float x1 = (w & 1) ? vaB1 : vaA1;
      const float x2 = (w & 1) ? vaB2 : vaA2;
      vaF[w * 3 + 0] = __shfl(x0, src, 64);
      vaF[w * 3 + 1] = __shfl(x1, src, 64);
      vaF[w * 3 + 2] = __shfl(x2, src, 64);
    }

    // ---- rec features: lane's v-subset ----
    const float* xr = x + (size_t)rec * 40;
    const float sbl0 = xr[s],      sbl1 = xr[4 + s];
    const float sbl2 = xr[8 + s],  sbl3 = xr[12 + s];
    const float vbA0 = xr[16 + s * 3 + 0], vbA1 = xr[16 + s * 3 + 1], vbA2 = xr[16 + s * 3 + 2];
    const float vbB0 = xr[16 + (s + 4) * 3 + 0], vbB1 = xr[16 + (s + 4) * 3 + 1], vbB2 = xr[16 + (s + 4) * 3 + 2];

    // ---- layer 2: two passes (row b with weight 1-f, row b+1 with weight f) ----
    float oe[20];
#pragma unroll
    for (int w = 0; w < 20; ++w) oe[w] = 0.f;
#pragma unroll
    for (int r = 0; r < 2; ++r) {
      const _Float16* __restrict__ Wr = r ? W1 : W0;
      const float cr = r ? f : (1.f - f);
      float so[8];
      float uo[12];
#pragma unroll
      for (int w = 0; w < 8; ++w) so[w] = 0.f;
#pragma unroll
      for (int w = 0; w < 12; ++w) uo[w] = 0.f;

      // W000 @ 576: [u:16][v:16][w:8], v = vv*4+s
#pragma unroll
      for (int u = 0; u < 16; ++u) {
        const float su = saF[u];
        const _Float16* rp = Wr + 576 + u * 128 + s * 8;
#pragma unroll
        for (int vv = 0; vv < 4; ++vv) {
          const float p = su * ((vv == 0) ? sbl0 : (vv == 1) ? sbl1 : (vv == 2) ? sbl2 : sbl3);
          h8 w = *(const h8*)(rp + vv * 32);
          so[0] += (float)w[0] * p; so[1] += (float)w[1] * p;
          so[2] += (float)w[2] * p; so[3] += (float)w[3] * p;
          so[4] += (float)w[4] * p; so[5] += (float)w[5] * p;
          so[6] += (float)w[6] * p; so[7] += (float)w[7] * p;
        }
      }
      // W110 @ 3648: [u:8][v:8][w:8], v = vv*4+s
#pragma unroll
      for (int u = 0; u < 8; ++u) {
        const float a0 = vaF[u * 3], a1 = vaF[u * 3 + 1], a2 = vaF[u * 3 + 2];
        const _Float16* rp = Wr + 3648 + u * 64 + s * 8;
#pragma unroll
        for (int vv = 0; vv < 2; ++vv) {
          const float b0v = vv ? vbB0 : vbA0;
          const float b1v = vv ? vbB1 : vbA1;
          const float b2v = vv ? vbB2 : vbA2;
          const float dd = (a0 * b0v + a1 * b1v + a2 * b2v) * INV_SQ3;
          h8 w = *(const h8*)(rp + vv * 32);
          so[0] += (float)w[0] * dd; so[1] += (float)w[1] * dd;
          so[2] += (float)w[2] * dd; so[3] += (float)w[3] * dd;
          so[4] += (float)w[4] * dd; so[5] += (float)w[5] * dd;
          so[6] += (float)w[6] * dd; so[7] += (float)w[7] * dd;
        }
      }
      // W011 @ 2624: [u:16][v:8][w:4], v = vv*4+s
#pragma unroll
      for (int u = 0; u < 16; ++u) {
        const float su = saF[u];
        const _Float16* rp = Wr + 2624 + u * 32 + s * 4;
#pragma unroll
        for (int vv = 0; vv < 2; ++vv) {
          const float q0 = su * (vv ? vbB0 : vbA0);
          const float q1 = su * (vv ? vbB1 : vbA1);
          const float q2 = su * (vv ? vbB2 : vbA2);
          h4 w = *(const h4*)(rp + vv * 16);
          const float w0f = (float)w[0], w1f = (float)w[1], w2f = (float)w[2], w3f = (float)w[3];
          uo[0] += w0f * q0; uo[1]  += w0f * q1; uo[2]  += w0f * q2;
          uo[3] += w1f * q0; uo[4]  += w1f * q1; uo[5]  += w1f * q2;
          uo[6] += w2f * q0; uo[7]  += w2f * q1; uo[8]  += w2f * q2;
          uo[9] += w3f * q0; uo[10] += w3f * q1; uo[11] += w3f * q2;
        }
      }
      // W101 @ 3136: [u:8][v:16][w:4], v = vv*4+s
#pragma unroll
      for (int u = 0; u < 8; ++u) {
        const float a0 = vaF[u * 3], a1 = vaF[u * 3 + 1], a2 = vaF[u * 3 + 2];
        const _Float16* rp = Wr + 3136 + u * 64 + s * 4;
#pragma unroll
        for (int vv = 0; vv < 4; ++vv) {
          const float sbv = (vv == 0) ? sbl0 : (vv == 1) ? sbl1 : (vv == 2) ? sbl2 : sbl3;
          const float q0 = a0 * sbv, q1 = a1 * sbv, q2 = a2 * sbv;
          h4 w = *(const h4*)(rp + vv * 16);
          const float w0f = (float)w[0], w1f = (float)w[1], w2f = (float)w[2], w3f = (float)w[3];
          uo[0] += w0f * q0; uo[1]  += w0f * q1; uo[2]  += w0f * q2;
          uo[3] += w1f * q0; uo[4]  += w1f * q1; uo[5]  += w1f * q2;
          uo[6] += w2f * q0; uo[7]  += w2f * q1; uo[8]  += w2f * q2;
          uo[9] += w3f * q0; uo[10] += w3f * q1; uo[11] += w3f * q2;
        }
      }
#pragma unroll
      for (int w = 0; w < 8; ++w)  oe[w]     += cr * so[w];
#pragma unroll
      for (int w = 0; w < 12; ++w) oe[8 + w] += cr * uo[w];
    }

    // ---- scale, quad butterfly reduce, store ----
#pragma unroll
    for (int w = 0; w < 8; ++w)  oe[w] *= C0_2F;
#pragma unroll
    for (int w = 0; w < 12; ++w) oe[8 + w] *= C1_2_OS3F;
#pragma unroll
    for (int w = 0; w < 20; ++w) {
      oe[w] += __shfl_xor(oe[w], 1, 64);
      oe[w] += __shfl_xor(oe[w], 2, 64);
    }
    if (s == 0) {
      float4* op = (float4*)(out + (size_t)e * 20);
#pragma unroll
      for (int j = 0; j < 5; ++j) {
        float4 o4;
        o4.x = oe[j * 4 + 0]; o4.y = oe[j * 4 + 1];
        o4.z = oe[j * 4 + 2]; o4.w = oe[j * 4 + 3];
        op[j] = o4;
      }
    }
  }
}

// ---------------- host ----------------
extern "C" void kernel_launch(void* const* d_in, const int* in_sizes, int n_in,
                              void* d_out, int out_size, void* d_ws, size_t ws_size,
                              hipStream_t stream) {
  const int*   ei  = (const int*)d_in[0];
  const float* pos = (const float*)d_in[1];
  const float* x   = (const float*)d_in[2];
  const float* lw1 = (const float*)d_in[3];
  const float* lw2 = (const float*)d_in[4];
  const float* rw1 = (const float*)d_in[5];
  const float* rw2 = (const float*)d_in[6];
  float* out = (float*)d_out;
  char*  ws  = (char*)d_ws;

  size_t o = 0;
  _Float16* lut = (_Float16*)(ws + o); o += (size_t)NLUT * NC * 2;
  o = (o + 15) & ~(size_t)15;
  int*   bin_e = (int*)(ws + o);  o += (size_t)NE * 4;
  float* f_e   = (float*)(ws + o); o += (size_t)NE * 4;
  int*   cnt   = (int*)(ws + o);  o += (size_t)GBIN * 4;
  int*   offs  = (int*)(ws + o);  o += (size_t)(GBIN + 1) * 4 + 12;
  int*   woff  = (int*)(ws + o);  o += (size_t)GBIN * 4;
  int*   sorted = (int*)(ws + o); o += (size_t)NE * 4;

  // ACT_C on host (runs at capture time, not in the timed graph)
  double ssum = 0.0;
  const double dz = 20.0 / 40000.0;
  for (int i = 0; i <= 40000; ++i) {
    const double z = -10.0 + dz * (double)i;
    const double sil = z / (1.0 + exp(-z));
    const double phi = exp(-0.5 * z * z) / sqrt(2.0 * M_PI);
    ssum += sil * sil * phi;
  }
  const float actc = (float)(1.0 / sqrt(ssum * dz));
  const float k0c  = (float)(1.14136 * exp(2.0));

  hipMemsetAsync(cnt, 0, GBIN * 4, stream);
  k_lut<<<dim3(129, 5), 256, 0, stream>>>(lw1, lw2, rw1, rw2, actc, k0c, lut);
  k_edge<<<(NE + 255) / 256, 256, 0, stream>>>(ei, pos, out, bin_e, f_e, cnt);
  k_scan<<<1, 256, 0, stream>>>(cnt, offs, woff);
  k_scatter<<<(NE + 255) / 256, 256, 0, stream>>>(bin_e, woff, sorted);
  k_epi<<<GBIN, 64, 0, stream>>>(lut, offs, sorted, f_e, ei, pos, x, out);
}

// Round 6
// 169.692 us; speedup vs baseline: 11.3099x; 11.3099x over previous
//
#include <hip/hip_runtime.h>
#include <math.h>

#define NE     50000
#define NNODE  10000
#define HDIM   128
#define GBIN   2048
#define NLUT   2049          // GBIN+1 rows
#define NC     4160          // 576 + 3584
#define NC1    576
#define NCHMAX 3611          // 2048 + ceil(50000/32)

typedef _Float16 h4 __attribute__((ext_vector_type(4)));
typedef _Float16 h8 __attribute__((ext_vector_type(8)));

// constants
#define SQ3C        1.7320508075688772f
#define INV_SQ3     0.5773502691896258f
#define C0_1F       0.20412414523193154f   // 1/sqrt(24)
#define C1_1_OS3F   0.20412414523193154f   // sqrt(3/24)/sqrt(3)
#define C0_2F       0.05590169943749474f   // 1/sqrt(320)
#define C1_2_OS3F   0.0625f                // sqrt(3/256)/sqrt(3)
#define INV_SQRT_H  0.08838834764831845f   // 1/sqrt(128)
#define DELTA       (5.0f/2048.0f)
#define INV_DELTA   409.6f
#define STEP_INV    (51.0f/5.0f)

// ---------------- K1: LUT build (fp16 output) ----------------
__global__ __launch_bounds__(256) void k_lut(
    const float* __restrict__ lw1, const float* __restrict__ lw2,
    const float* __restrict__ rw1, const float* __restrict__ rw2,
    const float actc, const float K0C, _Float16* __restrict__ lut) {
  __shared__ float Hs[256][20];
  const int pb = blockIdx.x;
  const int t  = threadIdx.x;
  {
    const int which = t >> 7, hc = t & 127;
    const float* __restrict__ w1 = which ? rw1 : lw1;
#pragma unroll
    for (int m = 0; m < 16; ++m) {
      const int g = pb * 16 + m;
      float h = 0.f;
      if (g <= GBIN) {
        const float d  = (float)g * DELTA;
        const float tt = d * STEP_INV;
        const int   i0 = (int)floorf(tt);
        float z = 0.f;
#pragma unroll
        for (int k = 0; k < 2; ++k) {
          const int ii = i0 + k;
          if (ii >= 1 && ii <= 50) {
            const float diff = tt - (float)ii;
            const float a = diff + 1.f, b = 1.f - diff;
            if (a > 0.f && b > 0.f) {
              const float val = K0C * __expf(-1.f / a - 1.f / b);
              z += val * w1[(ii - 1) * HDIM + hc];
            }
          }
        }
        h = actc * z / (1.f + __expf(-z)) * INV_SQRT_H;
      }
      Hs[t][m] = h;
    }
  }
  __syncthreads();

  const int n0 = blockIdx.y * 1024 + t * 4;
  if (n0 >= NC) return;
  const int isrec = (n0 >= NC1);
  const float* __restrict__ w2 = isrec ? (rw2 + (n0 - NC1)) : (lw2 + n0);
  const int stride = isrec ? 3584 : 576;
  const int hbase  = isrec ? 128 : 0;

  float acc[4][16];
#pragma unroll
  for (int c = 0; c < 4; ++c)
#pragma unroll
    for (int m = 0; m < 16; ++m) acc[c][m] = 0.f;

#pragma unroll 2
  for (int h = 0; h < HDIM; ++h) {
    const float4 wv = *(const float4*)(w2 + (size_t)h * stride);
    const float* hp = &Hs[hbase + h][0];
    const float4 m0 = *(const float4*)(hp);
    const float4 m1 = *(const float4*)(hp + 4);
    const float4 m2 = *(const float4*)(hp + 8);
    const float4 m3 = *(const float4*)(hp + 12);
    float hm[16];
    hm[0]=m0.x; hm[1]=m0.y; hm[2]=m0.z; hm[3]=m0.w;
    hm[4]=m1.x; hm[5]=m1.y; hm[6]=m1.z; hm[7]=m1.w;
    hm[8]=m2.x; hm[9]=m2.y; hm[10]=m2.z; hm[11]=m2.w;
    hm[12]=m3.x; hm[13]=m3.y; hm[14]=m3.z; hm[15]=m3.w;
    float wc[4]; wc[0]=wv.x; wc[1]=wv.y; wc[2]=wv.z; wc[3]=wv.w;
#pragma unroll
    for (int c = 0; c < 4; ++c)
#pragma unroll
      for (int m = 0; m < 16; ++m) acc[c][m] += wc[c] * hm[m];
  }

#pragma unroll
  for (int m = 0; m < 16; ++m) {
    const int g = pb * 16 + m;
    if (g <= GBIN) {
      h4 o;
      o[0] = (_Float16)acc[0][m]; o[1] = (_Float16)acc[1][m];
      o[2] = (_Float16)acc[2][m]; o[3] = (_Float16)acc[3][m];
      *(h4*)(lut + (size_t)g * NC + n0) = o;
    }
  }
}

// ---------------- K2: per-edge bin/frac + histogram; zero inactive outputs ----------------
__global__ void k_edge(const int* __restrict__ ei, const float* __restrict__ pos,
                       float* __restrict__ out, int* __restrict__ bin_e,
                       float* __restrict__ f_e, int* __restrict__ cnt) {
  const int e = blockIdx.x * 256 + threadIdx.x;
  if (e >= NE) return;
  const int rec = ei[e], lig = ei[NE + e];
  const float ax = pos[lig * 3 + 0] - pos[rec * 3 + 0];
  const float ay = pos[lig * 3 + 1] - pos[rec * 3 + 1];
  const float az = pos[lig * 3 + 2] - pos[rec * 3 + 2];
  const float d = sqrtf(ax * ax + ay * ay + az * az);
  if (d > 0.f && d < 5.0f) {
    const float tf = d * INV_DELTA;
    int b = (int)tf;
    if (b > GBIN - 1) b = GBIN - 1;
    bin_e[e] = b;
    f_e[e] = tf - (float)b;
    atomicAdd(&cnt[b], 1);
  } else {
    bin_e[e] = -1;
    float* o = out + (size_t)e * 20;
#pragma unroll
    for (int i2 = 0; i2 < 20; ++i2) o[i2] = 0.f;
  }
}

// ---------------- K3a: scan + chunk-table emission (single block) ----------------
__global__ void k_scan(const int* __restrict__ cnt, int* __restrict__ offs,
                       int* __restrict__ woff, int* __restrict__ chunk_bin,
                       int* __restrict__ chunk_start, int* __restrict__ nch) {
  __shared__ int lds[256];
  const int t = threadIdx.x;
  int loc[8];
  int s = 0;
#pragma unroll
  for (int i = 0; i < 8; ++i) { loc[i] = cnt[t * 8 + i]; s += loc[i]; }
  lds[t] = s;
  __syncthreads();
  for (int o = 1; o < 256; o <<= 1) {
    int v = 0;
    if (t >= o) v = lds[t - o];
    __syncthreads();
    lds[t] += v;
    __syncthreads();
  }
  int run = lds[t] - s;
  int runs[8];
#pragma unroll
  for (int i = 0; i < 8; ++i) {
    runs[i] = run;
    offs[t * 8 + i] = run;
    woff[t * 8 + i] = run;
    run += loc[i];
  }
  if (t == 255) offs[GBIN] = run;

  // second scan: chunk counts (ceil(count/32) per bin)
  int ccnt[8];
  int csum = 0;
#pragma unroll
  for (int i = 0; i < 8; ++i) { ccnt[i] = (loc[i] + 31) >> 5; csum += ccnt[i]; }
  __syncthreads();
  lds[t] = csum;
  __syncthreads();
  for (int o = 1; o < 256; o <<= 1) {
    int v = 0;
    if (t >= o) v = lds[t - o];
    __syncthreads();
    lds[t] += v;
    __syncthreads();
  }
  int crun = lds[t] - csum;
#pragma unroll
  for (int i = 0; i < 8; ++i) {
    for (int c = 0; c < ccnt[i]; ++c) {
      chunk_bin[crun]   = t * 8 + i;
      chunk_start[crun] = runs[i] + c * 32;
      ++crun;
    }
  }
  if (t == 255) nch[0] = lds[255];
}

// ---------------- K3b: counting-sort scatter ----------------
__global__ void k_scatter(const int* __restrict__ bin_e, int* __restrict__ woff,
                          int* __restrict__ sorted) {
  const int e = blockIdx.x * 256 + threadIdx.x;
  if (e >= NE) return;
  const int b = bin_e[e];
  if (b >= 0) {
    const int p = atomicAdd(&woff[b], 1);
    sorted[p] = e;
  }
}

// ---------------- K4: epilogue: one 32-edge chunk per 128-thread block ----------------
// Stage the chunk's bin rows (fp16 in HBM) as fp32 into LDS (convert once per chunk).
// 4 lanes per edge; layer 1 output-split + quad allgather; layer 2 v-split (v = vv*4+s),
// two row passes with weights (1-f), f.
__global__ __launch_bounds__(128) void k_epi(
    const _Float16* __restrict__ lut, const int* __restrict__ chunk_bin,
    const int* __restrict__ chunk_start, const int* __restrict__ offs,
    const int* __restrict__ sorted, const float* __restrict__ f_e,
    const int* __restrict__ ei, const float* __restrict__ pos,
    const float* __restrict__ x, float* __restrict__ out,
    const int* __restrict__ nch) {
  __shared__ float Wf[2 * NC];          // 33280 B
  const int bid = blockIdx.x;
  if (bid >= nch[0]) return;
  const int b     = chunk_bin[bid];
  const int start = chunk_start[bid];
  const int end0  = offs[b + 1];
  const int end   = (start + 32 < end0) ? (start + 32) : end0;
  const int tid = threadIdx.x;
  {  // stage 2 rows: 1040 h8 (16B) loads, cvt to fp32, 2x ds_write_b128 each
    const h8* src = (const h8*)(lut + (size_t)b * NC);
    for (int i = tid; i < 1040; i += 128) {
      h8 w = src[i];
      float4 lo, hi;
      lo.x = (float)w[0]; lo.y = (float)w[1]; lo.z = (float)w[2]; lo.w = (float)w[3];
      hi.x = (float)w[4]; hi.y = (float)w[5]; hi.z = (float)w[6]; hi.w = (float)w[7];
      *(float4*)&Wf[i * 8]     = lo;
      *(float4*)&Wf[i * 8 + 4] = hi;
    }
  }
  __syncthreads();
  const float* __restrict__ W0 = Wf;
  const float* __restrict__ W1 = Wf + NC;
  const int s  = tid & 3;
  const int qb = (tid & 63) & ~3;
  const int slot = start + (tid >> 2);
  if (slot >= end) return;

  const int e = sorted[slot];
  const float f = f_e[e];
  const int rec = ei[e], lig = ei[NE + e];
  const float ax = pos[lig * 3 + 0] - pos[rec * 3 + 0];
  const float ay = pos[lig * 3 + 1] - pos[rec * 3 + 1];
  const float az = pos[lig * 3 + 2] - pos[rec * 3 + 2];
  const float d = sqrtf(ax * ax + ay * ay + az * az);
  const float inv = SQ3C / fmaxf(d, 1e-12f);
  const float sh0 = ax * inv, sh1 = ay * inv, sh2 = az * inv;

  // ---- lig features ----
  float s1[16], v1[24];
  {
    const float4* xl = (const float4*)(x + (size_t)lig * 40);
#pragma unroll
    for (int j = 0; j < 4; ++j) {
      float4 v = xl[j];
      s1[j * 4 + 0] = v.x; s1[j * 4 + 1] = v.y; s1[j * 4 + 2] = v.z; s1[j * 4 + 3] = v.w;
    }
#pragma unroll
    for (int j = 0; j < 6; ++j) {
      float4 v = xl[4 + j];
      v1[j * 4 + 0] = v.x; v1[j * 4 + 1] = v.y; v1[j * 4 + 2] = v.z; v1[j * 4 + 3] = v.w;
    }
  }
  float vs[8];
#pragma unroll
  for (int u = 0; u < 8; ++u)
    vs[u] = (v1[u * 3] * sh0 + v1[u * 3 + 1] * sh1 + v1[u * 3 + 2] * sh2) * INV_SQ3;

  // ---- layer 1: sa (lane owns w = 4s..4s+3) ----
  float A0[4] = {0.f, 0.f, 0.f, 0.f}, A1[4] = {0.f, 0.f, 0.f, 0.f};
#pragma unroll
  for (int u = 0; u < 16; ++u) {   // W000 @ 0: [u:16][w:16]
    float4 w0 = *(const float4*)(W0 + u * 16 + s * 4);
    float4 w1 = *(const float4*)(W1 + u * 16 + s * 4);
    const float su = s1[u];
    A0[0] += w0.x * su; A0[1] += w0.y * su; A0[2] += w0.z * su; A0[3] += w0.w * su;
    A1[0] += w1.x * su; A1[1] += w1.y * su; A1[2] += w1.z * su; A1[3] += w1.w * su;
  }
#pragma unroll
  for (int u = 0; u < 8; ++u) {    // W110 @ 448: [u:8][w:16]
    float4 w0 = *(const float4*)(W0 + 448 + u * 16 + s * 4);
    float4 w1 = *(const float4*)(W1 + 448 + u * 16 + s * 4);
    const float su = vs[u];
    A0[0] += w0.x * su; A0[1] += w0.y * su; A0[2] += w0.z * su; A0[3] += w0.w * su;
    A1[0] += w1.x * su; A1[1] += w1.y * su; A1[2] += w1.z * su; A1[3] += w1.w * su;
  }
  const float sa0 = C0_1F * (A0[0] + f * (A1[0] - A0[0]));
  const float sa1 = C0_1F * (A0[1] + f * (A1[1] - A0[1]));
  const float sa2 = C0_1F * (A0[2] + f * (A1[2] - A0[2]));
  const float sa3 = C0_1F * (A0[3] + f * (A1[3] - A0[3]));

  // ---- layer 1: va (lane owns w = 2s, 2s+1) ----
  float vaA0, vaA1, vaA2, vaB0, vaB1, vaB2;
  {
    float cA0 = 0.f, cB0 = 0.f, cA1 = 0.f, cB1 = 0.f;
#pragma unroll
    for (int u = 0; u < 16; ++u) {  // W011 @ 256: [u:16][w:8]
      float2 w0 = *(const float2*)(W0 + 256 + u * 8 + s * 2);
      float2 w1 = *(const float2*)(W1 + 256 + u * 8 + s * 2);
      const float su = s1[u];
      cA0 += w0.x * su; cB0 += w0.y * su;
      cA1 += w1.x * su; cB1 += w1.y * su;
    }
    float tA0x=0.f,tA0y=0.f,tA0z=0.f, tB0x=0.f,tB0y=0.f,tB0z=0.f;
    float tA1x=0.f,tA1y=0.f,tA1z=0.f, tB1x=0.f,tB1y=0.f,tB1z=0.f;
#pragma unroll
    for (int u = 0; u < 8; ++u) {   // W101 @ 384: [u:8][w:8]
      float2 w0 = *(const float2*)(W0 + 384 + u * 8 + s * 2);
      float2 w1 = *(const float2*)(W1 + 384 + u * 8 + s * 2);
      const float p0 = v1[u * 3], p1 = v1[u * 3 + 1], p2 = v1[u * 3 + 2];
      tA0x += w0.x * p0; tA0y += w0.x * p1; tA0z += w0.x * p2;
      tB0x += w0.y * p0; tB0y += w0.y * p1; tB0z += w0.y * p2;
      tA1x += w1.x * p0; tA1y += w1.x * p1; tA1z += w1.x * p2;
      tB1x += w1.y * p0; tB1y += w1.y * p1; tB1z += w1.y * p2;
    }
    const float cA = cA0 + f * (cA1 - cA0);
    const float cB = cB0 + f * (cB1 - cB0);
    vaA0 = C1_1_OS3F * (cA * sh0 + (tA0x + f * (tA1x - tA0x)));
    vaA1 = C1_1_OS3F * (cA * sh1 + (tA0y + f * (tA1y - tA0y)));
    vaA2 = C1_1_OS3F * (cA * sh2 + (tA0z + f * (tA1z - tA0z)));
    vaB0 = C1_1_OS3F * (cB * sh0 + (tB0x + f * (tB1x - tB0x)));
    vaB1 = C1_1_OS3F * (cB * sh1 + (tB0y + f * (tB1y - tB0y)));
    vaB2 = C1_1_OS3F * (cB * sh2 + (tB0z + f * (tB1z - tB0z)));
  }

  // ---- quad allgather ----
  float saF[16];
#pragma unroll
  for (int k = 0; k < 16; ++k) {
    const float v = ((k & 3) == 0) ? sa0 : ((k & 3) == 1) ? sa1 : ((k & 3) == 2) ? sa2 : sa3;
    saF[k] = __shfl(v, qb + (k >> 2), 64);
  }
  float vaF[24];
#pragma unroll
  for (int w = 0; w < 8; ++w) {
    const int src = qb + (w >> 1);
    const float x0 = (w & 1) ? vaB0 : vaA0;
    const float x1 = (w & 1) ? vaB1 : vaA1;
    const float x2 = (w & 1) ? vaB2 : vaA2;
    vaF[w * 3 + 0] = __shfl(x0, src, 64);
    vaF[w * 3 + 1] = __shfl(x1, src, 64);
    vaF[w * 3 + 2] = __shfl(x2, src, 64);
  }

  // ---- rec features: lane's v-subset ----
  const float* xr = x + (size_t)rec * 40;
  const float sbl0 = xr[s],      sbl1 = xr[4 + s];
  const float sbl2 = xr[8 + s],  sbl3 = xr[12 + s];
  const float vbA0 = xr[16 + s * 3 + 0], vbA1 = xr[16 + s * 3 + 1], vbA2 = xr[16 + s * 3 + 2];
  const float vbB0 = xr[16 + (s + 4) * 3 + 0], vbB1 = xr[16 + (s + 4) * 3 + 1], vbB2 = xr[16 + (s + 4) * 3 + 2];

  // ---- layer 2: two row passes ----
  float oe[20];
#pragma unroll
  for (int w = 0; w < 20; ++w) oe[w] = 0.f;
#pragma unroll
  for (int r = 0; r < 2; ++r) {
    const float* __restrict__ Wr = r ? W1 : W0;
    const float cr = r ? f : (1.f - f);
    float so[8];
    float uo[12];
#pragma unroll
    for (int w = 0; w < 8; ++w) so[w] = 0.f;
#pragma unroll
    for (int w = 0; w < 12; ++w) uo[w] = 0.f;

    // W000 @ 576: [u:16][v:16][w:8], v = vv*4+s
#pragma unroll
    for (int u = 0; u < 16; ++u) {
      const float su = saF[u];
      const float* rp = Wr + 576 + u * 128 + s * 8;
#pragma unroll
      for (int vv = 0; vv < 4; ++vv) {
        const float p = su * ((vv == 0) ? sbl0 : (vv == 1) ? sbl1 : (vv == 2) ? sbl2 : sbl3);
        float4 wa = *(const float4*)(rp + vv * 32);
        float4 wb = *(const float4*)(rp + vv * 32 + 4);
        so[0] += wa.x * p; so[1] += wa.y * p; so[2] += wa.z * p; so[3] += wa.w * p;
        so[4] += wb.x * p; so[5] += wb.y * p; so[6] += wb.z * p; so[7] += wb.w * p;
      }
    }
    // W110 @ 3648: [u:8][v:8][w:8], v = vv*4+s
#pragma unroll
    for (int u = 0; u < 8; ++u) {
      const float a0 = vaF[u * 3], a1 = vaF[u * 3 + 1], a2 = vaF[u * 3 + 2];
      const float* rp = Wr + 3648 + u * 64 + s * 8;
#pragma unroll
      for (int vv = 0; vv < 2; ++vv) {
        const float b0v = vv ? vbB0 : vbA0;
        const float b1v = vv ? vbB1 : vbA1;
        const float b2v = vv ? vbB2 : vbA2;
        const float dd = (a0 * b0v + a1 * b1v + a2 * b2v) * INV_SQ3;
        float4 wa = *(const float4*)(rp + vv * 32);
        float4 wb = *(const float4*)(rp + vv * 32 + 4);
        so[0] += wa.x * dd; so[1] += wa.y * dd; so[2] += wa.z * dd; so[3] += wa.w * dd;
        so[4] += wb.x * dd; so[5] += wb.y * dd; so[6] += wb.z * dd; so[7] += wb.w * dd;
      }
    }
    // W011 @ 2624: [u:16][v:8][w:4], v = vv*4+s
#pragma unroll
    for (int u = 0; u < 16; ++u) {
      const float su = saF[u];
      const float* rp = Wr + 2624 + u * 32 + s * 4;
#pragma unroll
      for (int vv = 0; vv < 2; ++vv) {
        const float q0 = su * (vv ? vbB0 : vbA0);
        const float q1 = su * (vv ? vbB1 : vbA1);
        const float q2 = su * (vv ? vbB2 : vbA2);
        float4 w = *(const float4*)(rp + vv * 16);
        uo[0] += w.x * q0; uo[1]  += w.x * q1; uo[2]  += w.x * q2;
        uo[3] += w.y * q0; uo[4]  += w.y * q1; uo[5]  += w.y * q2;
        uo[6] += w.z * q0; uo[7]  += w.z * q1; uo[8]  += w.z * q2;
        uo[9] += w.w * q0; uo[10] += w.w * q1; uo[11] += w.w * q2;
      }
    }
    // W101 @ 3136: [u:8][v:16][w:4], v = vv*4+s
#pragma unroll
    for (int u = 0; u < 8; ++u) {
      const float a0 = vaF[u * 3], a1 = vaF[u * 3 + 1], a2 = vaF[u * 3 + 2];
      const float* rp = Wr + 3136 + u * 64 + s * 4;
#pragma unroll
      for (int vv = 0; vv < 4; ++vv) {
        const float sbv = (vv == 0) ? sbl0 : (vv == 1) ? sbl1 : (vv == 2) ? sbl2 : sbl3;
        const float q0 = a0 * sbv, q1 = a1 * sbv, q2 = a2 * sbv;
        float4 w = *(const float4*)(rp + vv * 16);
        uo[0] += w.x * q0; uo[1]  += w.x * q1; uo[2]  += w.x * q2;
        uo[3] += w.y * q0; uo[4]  += w.y * q1; uo[5]  += w.y * q2;
        uo[6] += w.z * q0; uo[7]  += w.z * q1; uo[8]  += w.z * q2;
        uo[9] += w.w * q0; uo[10] += w.w * q1; uo[11] += w.w * q2;
      }
    }
#pragma unroll
    for (int w = 0; w < 8; ++w)  oe[w]     += cr * so[w];
#pragma unroll
    for (int w = 0; w < 12; ++w) oe[8 + w] += cr * uo[w];
  }

  // ---- scale, quad butterfly reduce, store ----
#pragma unroll
  for (int w = 0; w < 8; ++w)  oe[w] *= C0_2F;
#pragma unroll
  for (int w = 0; w < 12; ++w) oe[8 + w] *= C1_2_OS3F;
#pragma unroll
  for (int w = 0; w < 20; ++w) {
    oe[w] += __shfl_xor(oe[w], 1, 64);
    oe[w] += __shfl_xor(oe[w], 2, 64);
  }
  if (s == 0) {
    float4* op = (float4*)(out + (size_t)e * 20);
#pragma unroll
    for (int j = 0; j < 5; ++j) {
      float4 o4;
      o4.x = oe[j * 4 + 0]; o4.y = oe[j * 4 + 1];
      o4.z = oe[j * 4 + 2]; o4.w = oe[j * 4 + 3];
      op[j] = o4;
    }
  }
}

// ---------------- host ----------------
extern "C" void kernel_launch(void* const* d_in, const int* in_sizes, int n_in,
                              void* d_out, int out_size, void* d_ws, size_t ws_size,
                              hipStream_t stream) {
  const int*   ei  = (const int*)d_in[0];
  const float* pos = (const float*)d_in[1];
  const float* x   = (const float*)d_in[2];
  const float* lw1 = (const float*)d_in[3];
  const float* lw2 = (const float*)d_in[4];
  const float* rw1 = (const float*)d_in[5];
  const float* rw2 = (const float*)d_in[6];
  float* out = (float*)d_out;
  char*  ws  = (char*)d_ws;

  size_t o = 0;
  _Float16* lut = (_Float16*)(ws + o); o += (size_t)NLUT * NC * 2;
  o = (o + 15) & ~(size_t)15;
  int*   bin_e = (int*)(ws + o);  o += (size_t)NE * 4;
  float* f_e   = (float*)(ws + o); o += (size_t)NE * 4;
  int*   cnt   = (int*)(ws + o);  o += (size_t)GBIN * 4;
  int*   offs  = (int*)(ws + o);  o += (size_t)(GBIN + 1) * 4 + 12;
  int*   woff  = (int*)(ws + o);  o += (size_t)GBIN * 4;
  int*   sorted = (int*)(ws + o); o += (size_t)NE * 4;
  int*   chunk_bin   = (int*)(ws + o); o += (size_t)NCHMAX * 4;
  int*   chunk_start = (int*)(ws + o); o += (size_t)NCHMAX * 4;
  int*   nch = (int*)(ws + o); o += 16;

  // ACT_C on host (runs at capture time, not in the timed graph)
  double ssum = 0.0;
  const double dz = 20.0 / 40000.0;
  for (int i = 0; i <= 40000; ++i) {
    const double z = -10.0 + dz * (double)i;
    const double sil = z / (1.0 + exp(-z));
    const double phi = exp(-0.5 * z * z) / sqrt(2.0 * M_PI);
    ssum += sil * sil * phi;
  }
  const float actc = (float)(1.0 / sqrt(ssum * dz));
  const float k0c  = (float)(1.14136 * exp(2.0));

  hipMemsetAsync(cnt, 0, GBIN * 4, stream);
  k_lut<<<dim3(129, 5), 256, 0, stream>>>(lw1, lw2, rw1, rw2, actc, k0c, lut);
  k_edge<<<(NE + 255) / 256, 256, 0, stream>>>(ei, pos, out, bin_e, f_e, cnt);
  k_scan<<<1, 256, 0, stream>>>(cnt, offs, woff, chunk_bin, chunk_start, nch);
  k_scatter<<<(NE + 255) / 256, 256, 0, stream>>>(bin_e, woff, sorted);
  k_epi<<<NCHMAX, 128, 0, stream>>>(lut, chunk_bin, chunk_start, offs, sorted, f_e,
                                    ei, pos, x, out, nch);
}